// Round 8
// baseline (42.479 us; speedup 1.0000x reference)
//
#include <hip/hip_runtime.h>

#define B_IMG 32
#define N_A   200000
#define N_C   10000

#define NCH    60                  // bbox chunks per image (units of 256; last takes tail)
#define BCH    3328                // 13 * 256
#define NCC    4                   // cls chunks per image
#define CCH    2560                // 10 * 256
#define SLOTS  64                  // 60 bbox + 4 cls
#define GRID   (B_IMG * SLOTS)     // 2048 = exactly 8 blocks/CU

// ws layout:
// doubles [0, 128): acc[j*4 + {0:focal_sum, 1:pos_count, 2:cls_sum, 3:pad}]
// byte 1024: unsigned int completion counter
// memset zeroes [0, 1028) every call.
#define WS_CTR_BYTES 1024
#define WS_ZERO_BYTES 1028

typedef float f4 __attribute__((ext_vector_type(4)));

// c = sigmoid(x); t=1: 0.25*(1-c)^2*(-log c); t=0: 0.75*c^2*(-log(1-c))
// -log(c) = log(1+e), e = exp(-x);  -log(1-c) = x + log(1+e);  1-c = e*c
__device__ __forceinline__ float focal_elem(float x, bool t) {
    float e = __expf(-x);
    float r = __builtin_amdgcn_rcpf(1.0f + e);   // c
    float L = __logf(1.0f + e);                  // softplus(-x)
    if (t) { float om = e * r; return 0.25f * om * om * L; }
    else   { return 0.75f * r * r * (x + L); }
}

__device__ __forceinline__ double wave_red(double v) {
#pragma unroll
    for (int o = 32; o; o >>= 1) v += __shfl_down(v, o, 64);
    return v;
}

// block = (j, slot): slot < 60 -> bbox chunk; slot >= 60 -> cls chunk (slot-60)
__global__ __launch_bounds__(256) void fused_kernel(
    const float* __restrict__ cls, const float* __restrict__ bd,
    const float* __restrict__ anc, const float* __restrict__ ann,
    const float* __restrict__ reg, double* __restrict__ ws,
    unsigned int* __restrict__ ctr, float* __restrict__ out)
{
    const int tid = threadIdx.x;
    const int lane = tid & 63, wv = tid >> 6;
    const int j  = blockIdx.x >> 6;     // image
    const int ch = blockIdx.x & 63;     // slot
    __shared__ double sred[2][4];
    __shared__ int s_last;
    const f4* __restrict__ anc4 = (const f4*)anc;

    if (ch < NCH) {
        const int a0 = ch * BCH;
        const int a1 = (ch == NCH - 1) ? N_A : (a0 + BCH);   // last chunk: 3648
        const int nfull = (a1 - a0) >> 8;                    // 13 (or 14)
        const float b0 = ann[j*7+0], b1 = ann[j*7+1], b2 = ann[j*7+2], b3 = ann[j*7+3];
        const float barea = (b2 - b0) * (b3 - b1);
        const float* __restrict__ bdr = bd + (size_t)j * N_A;

        float fsum = 0.0f, cnt = 0.0f;
        const int base = a0 + tid;
#pragma unroll 4
        for (int u = 0; u < nfull; ++u) {
            const int i = base + (u << 8);
            const f4 av = anc4[i];                           // x0,y0,x1,y1
            float iw = fmaxf(fminf(av.z, b2) - fmaxf(av.x, b0), 0.0f);
            float ih = fmaxf(fminf(av.w, b3) - fmaxf(av.y, b1), 0.0f);
            float inter = iw * ih;
            float ua = fmaxf((av.z - av.x) * (av.w - av.y) + barea - inter, 1e-8f);
            bool pos = (2.0f * inter >= ua);                 // inter/ua >= 0.5
            fsum += focal_elem(bdr[i], pos);
            cnt  += pos ? 1.0f : 0.0f;
        }
        {   // tail (only last chunk)
            const int i = base + (nfull << 8);
            if (i < a1) {
                const f4 av = anc4[i];
                float iw = fmaxf(fminf(av.z, b2) - fmaxf(av.x, b0), 0.0f);
                float ih = fmaxf(fminf(av.w, b3) - fmaxf(av.y, b1), 0.0f);
                float inter = iw * ih;
                float ua = fmaxf((av.z - av.x) * (av.w - av.y) + barea - inter, 1e-8f);
                bool pos = (2.0f * inter >= ua);
                fsum += focal_elem(bdr[i], pos);
                cnt  += pos ? 1.0f : 0.0f;
            }
        }
        double fv = wave_red((double)fsum);
        double cv = wave_red((double)cnt);
        if (lane == 0) { sred[0][wv] = fv; sred[1][wv] = cv; }
        __syncthreads();
        if (tid == 0) {
            atomicAdd(&ws[j * 4 + 0], sred[0][0] + sred[0][1] + sred[0][2] + sred[0][3]);
            atomicAdd(&ws[j * 4 + 1], sred[1][0] + sred[1][1] + sred[1][2] + sred[1][3]);
        }
    } else {
        const int cc = ch - NCH;            // cls chunk
        const int c0 = cc * CCH;
        const int c1 = (cc == NCC - 1) ? N_C : (c0 + CCH);   // last: 2320
        const int nfull = (c1 - c0) >> 8;
        const int n0 = (int)ann[j*7+4], n1 = (int)ann[j*7+5], n2 = (int)ann[j*7+6];
        const float* __restrict__ cj = cls + (size_t)j * N_C;
        float fsum = 0.0f;
        const int base = c0 + tid;
#pragma unroll 4
        for (int u = 0; u < nfull; ++u) {
            const int i = base + (u << 8);
            bool t = (i == n0) || (i == n1) || (i == n2);
            fsum += focal_elem(cj[i], t);
        }
        {
            const int i = base + (nfull << 8);
            if (i < c1) {
                bool t = (i == n0) || (i == n1) || (i == n2);
                fsum += focal_elem(cj[i], t);
            }
        }
        double v = wave_red((double)fsum);
        if (lane == 0) sred[0][wv] = v;
        __syncthreads();
        if (tid == 0)
            atomicAdd(&ws[j * 4 + 2], sred[0][0] + sred[0][1] + sred[0][2] + sred[0][3]);
    }

    // fan-in: order the counter bump behind this wave's partial atomics
    // (per-wave vmcnt wait — NOT a cache flush; atomics are device-coherent)
    if (tid == 0) {
        asm volatile("s_waitcnt vmcnt(0)" ::: "memory");
        unsigned int old = atomicAdd(ctr, 1u);
        s_last = (old == GRID - 1) ? 1 : 0;
    }
    __syncthreads();
    if (!s_last) return;

    // last block: finalize. Coherent reads via atomicAdd(p, 0.0).
    double cl = 0.0, bl = 0.0, rl = 0.0;
    if (tid < B_IMG) {
        const int jj = tid;
        double fsum = atomicAdd(&ws[jj * 4 + 0], 0.0);
        double npos = atomicAdd(&ws[jj * 4 + 1], 0.0);
        double csum = atomicAdd(&ws[jj * 4 + 2], 0.0);
        cl = csum / (double)N_C;
        bl = fsum / (double)N_A;

        float b0 = ann[jj*7+0], b1 = ann[jj*7+1], b2 = ann[jj*7+2], b3 = ann[jj*7+3];
        float gw_raw = b2 - b0, gh_raw = b3 - b1;
        float gx = b0 + 0.5f * gw_raw, gy = b1 + 0.5f * gh_raw;
        float gw = fmaxf(gw_raw, 1.0f), gh = fmaxf(gh_raw, 1.0f);
        double s[2];
#pragma unroll
        for (int p = 0; p < 2; ++p) {
            float x0 = anc[p*4+0], y0 = anc[p*4+1], x1 = anc[p*4+2], y1 = anc[p*4+3];
            float aw = x1 - x0, ah = y1 - y0;
            float ax = x0 + 0.5f * aw, ay = y0 + 0.5f * ah;
            float tg[4];
            tg[0] = ((gx - ax) / aw) / 0.1f;
            tg[1] = ((gy - ay) / ah) / 0.1f;
            tg[2] = logf(gw / aw) / 0.2f;
            tg[3] = logf(gh / ah) / 0.2f;
            const float* rj = reg + (size_t)jj * N_A * 4 + p * 4;
            double ssum = 0.0;
#pragma unroll
            for (int k = 0; k < 4; ++k) {
                float d = fabsf(tg[k] - rj[k]);
                float v = (d <= (1.0f / 9.0f)) ? (0.5f * 9.0f * d * d) : (d - 0.5f / 9.0f);
                ssum += (double)v;
            }
            s[p] = ssum;
        }
        double rlv = (((double)N_A - npos) * s[0] + npos * s[1]) / (4.0 * (double)N_A);
        rl = (npos > 0.0) ? rlv : 0.0;
    }
    if (tid < 64) {
        cl = wave_red(cl);
        bl = wave_red(bl);
        rl = wave_red(rl);
        if (tid == 0) {
            out[0] = (float)(cl / B_IMG);
            out[1] = (float)(bl / B_IMG);
            out[2] = (float)(rl / B_IMG);
        }
    }
}

extern "C" void kernel_launch(void* const* d_in, const int* in_sizes, int n_in,
                              void* d_out, int out_size, void* d_ws, size_t ws_size,
                              hipStream_t stream) {
    const float* cls = (const float*)d_in[0];   // (32, 10000)
    const float* reg = (const float*)d_in[1];   // (32, 200000, 4)
    const float* bd  = (const float*)d_in[2];   // (32, 200000)
    const float* anc = (const float*)d_in[3];   // (1, 200000, 4)
    const float* ann = (const float*)d_in[4];   // (32, 1, 7)
    float* out = (float*)d_out;                 // 3 floats
    double* ws = (double*)d_ws;
    unsigned int* ctr = (unsigned int*)((char*)d_ws + WS_CTR_BYTES);

    hipMemsetAsync(d_ws, 0, WS_ZERO_BYTES, stream);
    hipLaunchKernelGGL(fused_kernel, dim3(GRID), dim3(256), 0, stream,
                       cls, bd, anc, ann, reg, ws, ctr, out);
}

// Round 11
// 42.158 us; speedup vs baseline: 1.0076x; 1.0076x over previous
//
#include <hip/hip_runtime.h>

#define B_IMG 32
#define N_A   200000
#define N_C   10000

#define NCH    60                  // bbox chunks per image (units of 256; last takes tail)
#define BCH    3328                // 13 * 256
#define NCC    4                   // cls chunks per image
#define CCH    2560                // 10 * 256
#define SLOTS  64                  // 60 bbox + 4 cls
#define GRID   (B_IMG * SLOTS)     // 2048 = exactly 8 blocks/CU

// ws layout (u64 slots; ALL cross-block data moves via HW RMW atomics only):
// [0, 2048)        focal partial bits [j*64 + slot] (cls slots 60..63 = 0.0)
// [2048, 4096)     pos-cnt partial bits [j*64 + slot]
// [4096, 4224)     cls partial bits [j*4 + cc]
// [4224, 4352)     per-image results bits [j*4 + {0:cl,1:bl,2:rl}]
// bytes [34816, 34944): u32 img_ctr[32]; byte 34944: u32 global ctr.
// Counters ARE memset to 0 each call (132 bytes) — round-9/10 lesson: the
// "mod-64 from any base" election fires EARLY from a poisoned base (0xAA...
// = 42 mod 64 -> fires at bump 22, before all 64 blocks finished).
#define D_FOCAL 0
#define D_CNT   (B_IMG * SLOTS)
#define D_CLS   (2 * B_IMG * SLOTS)
#define D_RES   (2 * B_IMG * SLOTS + B_IMG * NCC)
#define CTR_BYTE_OFF ((size_t)(D_RES + B_IMG * 4) * 8)   // 34816
#define CTR_ZERO_BYTES (B_IMG * 4 + 4)                   // 132

typedef float f4 __attribute__((ext_vector_type(4)));
typedef unsigned long long u64;

// coherent hand-off: write = HW 64-bit swap; read = HW 64-bit or-with-0.
// RMW atomics serialize at the device coherent point (proven: round-7 fused
// version with RMW adds + zeroed counter passed). Plain loads/stores hit the
// non-coherent per-XCD L2 and must not be used for cross-block data.
__device__ __forceinline__ void slot_write(u64* p, double v) {
    u64 old = __hip_atomic_exchange(p, (u64)__double_as_longlong(v),
                                    __ATOMIC_RELAXED, __HIP_MEMORY_SCOPE_AGENT);
    asm volatile("" :: "v"(old) : "memory");   // consume old; keep returning form
}
__device__ __forceinline__ double slot_read(u64* p) {
    u64 bits = __hip_atomic_fetch_or(p, 0ull, __ATOMIC_RELAXED, __HIP_MEMORY_SCOPE_AGENT);
    return __longlong_as_double((long long)bits);
}

// c = sigmoid(x); t=1: 0.25*(1-c)^2*(-log c); t=0: 0.75*c^2*(-log(1-c))
__device__ __forceinline__ float focal_elem(float x, bool t) {
    float e = __expf(-x);
    float r = __builtin_amdgcn_rcpf(1.0f + e);   // c
    float L = __logf(1.0f + e);                  // softplus(-x)
    if (t) { float om = e * r; return 0.25f * om * om * L; }
    else   { return 0.75f * r * r * (x + L); }
}

__device__ __forceinline__ double wave_red(double v) {
#pragma unroll
    for (int o = 32; o; o >>= 1) v += __shfl_down(v, o, 64);
    return v;
}

// block = (j, slot): slot < 60 -> bbox chunk; slot >= 60 -> cls chunk (slot-60)
__global__ __launch_bounds__(256) void fused_kernel(
    const float* __restrict__ cls, const float* __restrict__ bd,
    const float* __restrict__ anc, const float* __restrict__ ann,
    const float* __restrict__ reg, u64* __restrict__ ws,
    unsigned int* __restrict__ ictr, unsigned int* __restrict__ gctr,
    float* __restrict__ out)
{
    const int tid = threadIdx.x;
    const int lane = tid & 63, wv = tid >> 6;
    const int j  = blockIdx.x >> 6;     // image
    const int ch = blockIdx.x & 63;     // slot
    __shared__ double sred[2][4];
    __shared__ int s_lead;
    const f4* __restrict__ anc4 = (const f4*)anc;

    if (ch < NCH) {
        const int a0 = ch * BCH;
        const int a1 = (ch == NCH - 1) ? N_A : (a0 + BCH);   // last chunk: 3648
        const int nfull = (a1 - a0) >> 8;
        const float b0 = ann[j*7+0], b1 = ann[j*7+1], b2 = ann[j*7+2], b3 = ann[j*7+3];
        const float barea = (b2 - b0) * (b3 - b1);
        const float* __restrict__ bdr = bd + (size_t)j * N_A;

        float fsum = 0.0f, cnt = 0.0f;
        const int base = a0 + tid;
#pragma unroll 4
        for (int u = 0; u < nfull; ++u) {
            const int i = base + (u << 8);
            const f4 av = anc4[i];
            float iw = fmaxf(fminf(av.z, b2) - fmaxf(av.x, b0), 0.0f);
            float ih = fmaxf(fminf(av.w, b3) - fmaxf(av.y, b1), 0.0f);
            float inter = iw * ih;
            float ua = fmaxf((av.z - av.x) * (av.w - av.y) + barea - inter, 1e-8f);
            bool pos = (2.0f * inter >= ua);
            fsum += focal_elem(bdr[i], pos);
            cnt  += pos ? 1.0f : 0.0f;
        }
        {   // tail (last chunk only)
            const int i = base + (nfull << 8);
            if (i < a1) {
                const f4 av = anc4[i];
                float iw = fmaxf(fminf(av.z, b2) - fmaxf(av.x, b0), 0.0f);
                float ih = fmaxf(fminf(av.w, b3) - fmaxf(av.y, b1), 0.0f);
                float inter = iw * ih;
                float ua = fmaxf((av.z - av.x) * (av.w - av.y) + barea - inter, 1e-8f);
                bool pos = (2.0f * inter >= ua);
                fsum += focal_elem(bdr[i], pos);
                cnt  += pos ? 1.0f : 0.0f;
            }
        }
        double fv = wave_red((double)fsum);
        double cv = wave_red((double)cnt);
        if (lane == 0) { sred[0][wv] = fv; sred[1][wv] = cv; }
        __syncthreads();
        if (tid == 0) {
            slot_write(&ws[D_FOCAL + j * SLOTS + ch], sred[0][0] + sred[0][1] + sred[0][2] + sred[0][3]);
            slot_write(&ws[D_CNT   + j * SLOTS + ch], sred[1][0] + sred[1][1] + sred[1][2] + sred[1][3]);
        }
    } else {
        const int cc = ch - NCH;
        const int c0 = cc * CCH;
        const int c1 = (cc == NCC - 1) ? N_C : (c0 + CCH);   // last: 2320
        const int nfull = (c1 - c0) >> 8;
        const int n0 = (int)ann[j*7+4], n1 = (int)ann[j*7+5], n2 = (int)ann[j*7+6];
        const float* __restrict__ cj = cls + (size_t)j * N_C;
        float fsum = 0.0f;
        const int base = c0 + tid;
#pragma unroll 4
        for (int u = 0; u < nfull; ++u) {
            const int i = base + (u << 8);
            bool t = (i == n0) || (i == n1) || (i == n2);
            fsum += focal_elem(cj[i], t);
        }
        {
            const int i = base + (nfull << 8);
            if (i < c1) {
                bool t = (i == n0) || (i == n1) || (i == n2);
                fsum += focal_elem(cj[i], t);
            }
        }
        double v = wave_red((double)fsum);
        if (lane == 0) sred[0][wv] = v;
        __syncthreads();
        if (tid == 0) {
            slot_write(&ws[D_CLS + j * NCC + cc], sred[0][0] + sred[0][1] + sred[0][2] + sred[0][3]);
            slot_write(&ws[D_FOCAL + j * SLOTS + ch], 0.0);   // keep leader's 64-lane scan uniform
            slot_write(&ws[D_CNT   + j * SLOTS + ch], 0.0);
        }
    }

    // ---- image fan-in: the 64th finisher of image j becomes image-leader ----
    if (tid == 0) {
        asm volatile("s_waitcnt vmcnt(0)" ::: "memory");   // swaps acked at coherent point
        unsigned int old = __hip_atomic_fetch_add(&ictr[j], 1u, __ATOMIC_RELAXED,
                                                  __HIP_MEMORY_SCOPE_AGENT);
        s_lead = (old == 63u) ? 1 : 0;                     // counter memset to 0 each call
    }
    __syncthreads();
    if (!s_lead) return;
    if (tid >= 64) return;              // leader work in wave 0 only; no more barriers

    // per-image reduction — coherent RMW reads
    double f = slot_read(&ws[D_FOCAL + j * SLOTS + lane]);
    double c = slot_read(&ws[D_CNT   + j * SLOTS + lane]);
    double s = (lane < NCC) ? slot_read(&ws[D_CLS + j * NCC + lane]) : 0.0;
    f = wave_red(f); c = wave_red(c); s = wave_red(s);

    if (lane == 0) {
        double bl = f / (double)N_A;
        double cl = s / (double)N_C;
        double npos = c;
        float b0 = ann[j*7+0], b1 = ann[j*7+1], b2 = ann[j*7+2], b3 = ann[j*7+3];
        float gw_raw = b2 - b0, gh_raw = b3 - b1;
        float gx = b0 + 0.5f * gw_raw, gy = b1 + 0.5f * gh_raw;
        float gw = fmaxf(gw_raw, 1.0f), gh = fmaxf(gh_raw, 1.0f);
        double sp[2];
#pragma unroll
        for (int p = 0; p < 2; ++p) {
            float x0 = anc[p*4+0], y0 = anc[p*4+1], x1 = anc[p*4+2], y1 = anc[p*4+3];
            float aw = x1 - x0, ah = y1 - y0;
            float ax = x0 + 0.5f * aw, ay = y0 + 0.5f * ah;
            float tg[4];
            tg[0] = ((gx - ax) / aw) / 0.1f;
            tg[1] = ((gy - ay) / ah) / 0.1f;
            tg[2] = logf(gw / aw) / 0.2f;
            tg[3] = logf(gh / ah) / 0.2f;
            const float* rj = reg + (size_t)j * N_A * 4 + p * 4;
            double ssum = 0.0;
#pragma unroll
            for (int k = 0; k < 4; ++k) {
                float d = fabsf(tg[k] - rj[k]);
                float v = (d <= (1.0f / 9.0f)) ? (0.5f * 9.0f * d * d) : (d - 0.5f / 9.0f);
                ssum += (double)v;
            }
            sp[p] = ssum;
        }
        double rlv = (((double)N_A - npos) * sp[0] + npos * sp[1]) / (4.0 * (double)N_A);
        double rl = (npos > 0.0) ? rlv : 0.0;
        slot_write(&ws[D_RES + j * 4 + 0], cl);
        slot_write(&ws[D_RES + j * 4 + 1], bl);
        slot_write(&ws[D_RES + j * 4 + 2], rl);
    }

    // ---- global fan-in: the 32nd image-leader averages and writes out ----
    unsigned int old2 = 0;
    if (lane == 0) {
        asm volatile("s_waitcnt vmcnt(0)" ::: "memory");
        old2 = __hip_atomic_fetch_add(gctr, 1u, __ATOMIC_RELAXED, __HIP_MEMORY_SCOPE_AGENT);
    }
    int fin = __shfl((int)(old2 == 31u), 0, 64);
    if (!fin) return;

    double cl = 0.0, bl = 0.0, rl = 0.0;
    if (lane < B_IMG) {
        cl = slot_read(&ws[D_RES + lane * 4 + 0]);
        bl = slot_read(&ws[D_RES + lane * 4 + 1]);
        rl = slot_read(&ws[D_RES + lane * 4 + 2]);
    }
    cl = wave_red(cl); bl = wave_red(bl); rl = wave_red(rl);
    if (lane == 0) {
        out[0] = (float)(cl / B_IMG);
        out[1] = (float)(bl / B_IMG);
        out[2] = (float)(rl / B_IMG);
    }
}

extern "C" void kernel_launch(void* const* d_in, const int* in_sizes, int n_in,
                              void* d_out, int out_size, void* d_ws, size_t ws_size,
                              hipStream_t stream) {
    const float* cls = (const float*)d_in[0];   // (32, 10000)
    const float* reg = (const float*)d_in[1];   // (32, 200000, 4)
    const float* bd  = (const float*)d_in[2];   // (32, 200000)
    const float* anc = (const float*)d_in[3];   // (1, 200000, 4)
    const float* ann = (const float*)d_in[4];   // (32, 1, 7)
    float* out = (float*)d_out;                 // 3 floats
    u64* ws = (u64*)d_ws;
    unsigned int* ictr = (unsigned int*)((char*)d_ws + CTR_BYTE_OFF);
    unsigned int* gctr = ictr + B_IMG;

    hipMemsetAsync(ictr, 0, CTR_ZERO_BYTES, stream);
    hipLaunchKernelGGL(fused_kernel, dim3(GRID), dim3(256), 0, stream,
                       cls, bd, anc, ann, reg, ws, ictr, gctr, out);
}

// Round 12
// 26.196 us; speedup vs baseline: 1.6216x; 1.6093x over previous
//
#include <hip/hip_runtime.h>

#define B_IMG 32
#define N_A   200000
#define N_C   10000

#define NCH    60                  // bbox chunks per image; chunks 0..58 = 3328, chunk 59 = 3648
#define BCH    3328                // 13 * 256
#define NCC    4                   // cls chunks; 0..2 = 2560 (10*256), 3 = 2320 (9*256+16)
#define CCH    2560
#define SLOTS  64                  // 60 bbox + 4 cls
#define GRID   (B_IMG * SLOTS)     // 2048 = exactly 8 blocks/CU

// ws layout (doubles) — every slot written every call before final reads it:
// [0, 2048)     focal partial [j*64 + slot]  (cls slots 60..63 written 0.0)
// [2048, 4096)  pos-cnt partial [j*64 + slot] (cls slots written 0.0)
// [4096, 4224)  cls partial [j*4 + cc]
#define D_FOCAL 0
#define D_CNT   (B_IMG * SLOTS)
#define D_CLS   (2 * B_IMG * SLOTS)

typedef float f4 __attribute__((ext_vector_type(4)));

// c = sigmoid(x); t=1: 0.25*(1-c)^2*(-log c); t=0: 0.75*c^2*(-log(1-c))
__device__ __forceinline__ float focal_elem(float x, bool t) {
    float e = __expf(-x);
    float r = __builtin_amdgcn_rcpf(1.0f + e);   // c
    float L = __logf(1.0f + e);                  // softplus(-x)
    if (t) { float om = e * r; return 0.25f * om * om * L; }
    else   { return 0.75f * r * r * (x + L); }
}

__device__ __forceinline__ double wave_red(double v) {
#pragma unroll
    for (int o = 32; o; o >>= 1) v += __shfl_down(v, o, 64);
    return v;
}

__device__ __forceinline__ void iou_step(const f4 av, float x,
                                         float b0, float b1, float b2, float b3,
                                         float barea, float& fsum, float& cnt) {
    float iw = fmaxf(fminf(av.z, b2) - fmaxf(av.x, b0), 0.0f);
    float ih = fmaxf(fminf(av.w, b3) - fmaxf(av.y, b1), 0.0f);
    float inter = iw * ih;
    float ua = fmaxf((av.z - av.x) * (av.w - av.y) + barea - inter, 1e-8f);
    bool pos = (2.0f * inter >= ua);             // inter/ua >= 0.5
    fsum += focal_elem(x, pos);
    cnt  += pos ? 1.0f : 0.0f;
}

// block = (j, slot): slot < 60 -> bbox chunk; slot >= 60 -> cls chunk (slot-60)
__global__ __launch_bounds__(256) void main_kernel(
    const float* __restrict__ cls, const float* __restrict__ bd,
    const float* __restrict__ anc, const float* __restrict__ ann,
    double* __restrict__ ws)
{
    const int tid = threadIdx.x;
    const int lane = tid & 63, wv = tid >> 6;
    const int j  = blockIdx.x >> 6;     // image
    const int ch = blockIdx.x & 63;     // slot
    __shared__ double sred[2][4];
    const f4* __restrict__ anc4 = (const f4*)anc;

    if (ch < NCH) {
        const int a0 = ch * BCH;
        const float b0 = ann[j*7+0], b1 = ann[j*7+1], b2 = ann[j*7+2], b3 = ann[j*7+3];
        const float barea = (b2 - b0) * (b3 - b1);
        const float* __restrict__ bdr = bd + (size_t)j * N_A;

        float fsum = 0.0f, cnt = 0.0f;
        const int base = a0 + tid;
        // compile-time trip count -> full unroll, all loads issued up front (MLP)
#pragma unroll
        for (int u = 0; u < 13; ++u) {
            const int i = base + (u << 8);
            iou_step(anc4[i], bdr[i], b0, b1, b2, b3, barea, fsum, cnt);
        }
        if (ch == NCH - 1) {            // chunk 59 tail: 3648 = 14*256 + 64
            int i = base + (13 << 8);
            iou_step(anc4[i], bdr[i], b0, b1, b2, b3, barea, fsum, cnt);
            if (tid < 64) {
                i = base + (14 << 8);
                iou_step(anc4[i], bdr[i], b0, b1, b2, b3, barea, fsum, cnt);
            }
        }
        double fv = wave_red((double)fsum);
        double cv = wave_red((double)cnt);
        if (lane == 0) { sred[0][wv] = fv; sred[1][wv] = cv; }
        __syncthreads();
        if (tid == 0) {
            ws[D_FOCAL + j * SLOTS + ch] = sred[0][0] + sred[0][1] + sred[0][2] + sred[0][3];
            ws[D_CNT   + j * SLOTS + ch] = sred[1][0] + sred[1][1] + sred[1][2] + sred[1][3];
        }
    } else {
        const int cc = ch - NCH;
        const int c0 = cc * CCH;
        const int n0 = (int)ann[j*7+4], n1 = (int)ann[j*7+5], n2 = (int)ann[j*7+6];
        const float* __restrict__ cj = cls + (size_t)j * N_C;
        float fsum = 0.0f;
        const int base = c0 + tid;
#pragma unroll
        for (int u = 0; u < 9; ++u) {
            const int i = base + (u << 8);
            bool t = (i == n0) || (i == n1) || (i == n2);
            fsum += focal_elem(cj[i], t);
        }
        if (cc < NCC - 1) {             // chunks 0..2: 10th unit
            const int i = base + (9 << 8);
            bool t = (i == n0) || (i == n1) || (i == n2);
            fsum += focal_elem(cj[i], t);
        } else if (tid < 16) {          // chunk 3: 2320 = 9*256 + 16
            const int i = base + (9 << 8);
            bool t = (i == n0) || (i == n1) || (i == n2);
            fsum += focal_elem(cj[i], t);
        }
        double v = wave_red((double)fsum);
        if (lane == 0) sred[0][wv] = v;
        __syncthreads();
        if (tid == 0) {
            ws[D_CLS + j * NCC + cc] = sred[0][0] + sred[0][1] + sred[0][2] + sred[0][3];
            ws[D_FOCAL + j * SLOTS + ch] = 0.0;   // keep final's 64-lane scan uniform
            ws[D_CNT   + j * SLOTS + ch] = 0.0;
        }
    }
}

// 1024 threads = 16 waves; wave w reduces images w and w+16 (lane-parallel loads)
__global__ __launch_bounds__(1024) void final_kernel(
    const float* __restrict__ anc, const float* __restrict__ ann,
    const float* __restrict__ reg, const double* __restrict__ ws,
    float* __restrict__ out)
{
    const int tid = threadIdx.x;
    const int lane = tid & 63, wv = tid >> 6;
    __shared__ double res[B_IMG][3];

#pragma unroll
    for (int half = 0; half < 2; ++half) {
        const int j = wv + half * 16;
        double f = ws[D_FOCAL + j * SLOTS + lane];
        double c = ws[D_CNT   + j * SLOTS + lane];
        double s = (lane < NCC) ? ws[D_CLS + j * NCC + lane] : 0.0;
        f = wave_red(f); c = wave_red(c); s = wave_red(s);
        if (lane == 0) {
            double bl = f / (double)N_A;
            double cl = s / (double)N_C;
            double npos = c;
            float b0 = ann[j*7+0], b1 = ann[j*7+1], b2 = ann[j*7+2], b3 = ann[j*7+3];
            float gw_raw = b2 - b0, gh_raw = b3 - b1;
            float gx = b0 + 0.5f * gw_raw, gy = b1 + 0.5f * gh_raw;
            float gw = fmaxf(gw_raw, 1.0f), gh = fmaxf(gh_raw, 1.0f);
            double sp[2];
#pragma unroll
            for (int p = 0; p < 2; ++p) {
                float x0 = anc[p*4+0], y0 = anc[p*4+1], x1 = anc[p*4+2], y1 = anc[p*4+3];
                float aw = x1 - x0, ah = y1 - y0;
                float ax = x0 + 0.5f * aw, ay = y0 + 0.5f * ah;
                float tg[4];
                tg[0] = ((gx - ax) / aw) / 0.1f;
                tg[1] = ((gy - ay) / ah) / 0.1f;
                tg[2] = logf(gw / aw) / 0.2f;
                tg[3] = logf(gh / ah) / 0.2f;
                const float* rj = reg + (size_t)j * N_A * 4 + p * 4;
                double ssum = 0.0;
#pragma unroll
                for (int k = 0; k < 4; ++k) {
                    float d = fabsf(tg[k] - rj[k]);
                    float v = (d <= (1.0f / 9.0f)) ? (0.5f * 9.0f * d * d) : (d - 0.5f / 9.0f);
                    ssum += (double)v;
                }
                sp[p] = ssum;
            }
            double rlv = (((double)N_A - npos) * sp[0] + npos * sp[1]) / (4.0 * (double)N_A);
            res[j][0] = cl;
            res[j][1] = bl;
            res[j][2] = (npos > 0.0) ? rlv : 0.0;
        }
    }
    __syncthreads();
    if (tid < 64) {
        double cl = 0.0, bl = 0.0, rl = 0.0;
        if (lane < B_IMG) { cl = res[lane][0]; bl = res[lane][1]; rl = res[lane][2]; }
        cl = wave_red(cl); bl = wave_red(bl); rl = wave_red(rl);
        if (lane == 0) {
            out[0] = (float)(cl / B_IMG);
            out[1] = (float)(bl / B_IMG);
            out[2] = (float)(rl / B_IMG);
        }
    }
}

extern "C" void kernel_launch(void* const* d_in, const int* in_sizes, int n_in,
                              void* d_out, int out_size, void* d_ws, size_t ws_size,
                              hipStream_t stream) {
    const float* cls = (const float*)d_in[0];   // (32, 10000)
    const float* reg = (const float*)d_in[1];   // (32, 200000, 4)
    const float* bd  = (const float*)d_in[2];   // (32, 200000)
    const float* anc = (const float*)d_in[3];   // (1, 200000, 4)
    const float* ann = (const float*)d_in[4];   // (32, 1, 7)
    float* out = (float*)d_out;                 // 3 floats
    double* ws = (double*)d_ws;

    hipLaunchKernelGGL(main_kernel, dim3(GRID), dim3(256), 0, stream,
                       cls, bd, anc, ann, ws);
    hipLaunchKernelGGL(final_kernel, dim3(1), dim3(1024), 0, stream,
                       anc, ann, reg, ws, out);
}